// Round 3
// baseline (532.423 us; speedup 1.0000x reference)
//
#include <hip/hip_runtime.h>

// DetectionLoss: B=16, A=65536, T=32, C=21.
// R3: main does NO per-cell histogram (1 LDS atomic/thread on a 512-bin
// anchor-max histogram; LDS ~24KB -> 6 blocks/CU). Threshold v = bin edge of
// k-th largest per-anchor max focal => all top-k cells >= v. collect kernel
// gathers candidate anchors (maxb >= v) compactly + builds exact 4096-bin cell
// histogram over cells >= v; 3-level radix select runs over candidates only.

#define AN 65536
#define BN 16
#define TN 32
#define CN 21
#define NBA 512
#define NB1 4096

struct Accum { double pos_sum; double bbox_sum; double all_sum; unsigned num_pos; unsigned n_neg; };
struct Chain { double sumAbove; double topk; unsigned active; unsigned vbits; unsigned k;
               unsigned b1; unsigned b2; unsigned rem; };

// ---------- shared math (bit-identical across kernels: _rn intrinsics) ----------
__device__ __forceinline__ void softmax_row(const float* __restrict__ row, float* __restrict__ p) {
    float c[CN];
#pragma unroll
    for (int j = 0; j < CN; ++j) c[j] = row[j];
    float m = c[0];
#pragma unroll
    for (int j = 1; j < CN; ++j) m = fmaxf(m, c[j]);
    float s = 0.f;
#pragma unroll
    for (int j = 0; j < CN; ++j) { c[j] = __expf(__fsub_rn(c[j], m)); s = __fadd_rn(s, c[j]); }
    float inv = 1.0f / s;
#pragma unroll
    for (int j = 0; j < CN; ++j) p[j] = __fmul_rn(c[j], inv);
}

__device__ __forceinline__ float focal_cell(float p, bool cellpos) {
    float pt = cellpos ? p : __fsub_rn(1.0f, p);
    float af = cellpos ? 0.25f : 0.75f;
    float om = __fsub_rn(1.0f, pt);
    float lg = __logf(fmaxf(pt, 1e-6f));
    return __fmul_rn(__fmul_rn(__fmul_rn(-af, om), om), lg);
}

__device__ __forceinline__ unsigned focal_bits(float fo) {
    unsigned bits = __float_as_uint(fo);
    if (bits == 0x80000000u) bits = 0u;  // canonicalize -0.0
    return bits;
}

// ---------- kernel A: matching ----------
__global__ __launch_bounds__(256) void match_kernel(
    const float4* __restrict__ anchors, const float4* __restrict__ tboxes,
    float* __restrict__ max_iou, unsigned char* __restrict__ best_t,
    unsigned long long* __restrict__ gbest)
{
    __shared__ float4 tbS[TN];
    __shared__ float iouS[256 * (TN + 1)];
    __shared__ float pbV[TN][8];
    __shared__ int   pbA[TN][8];
    int b = blockIdx.y, tid = threadIdx.x;
    int a = blockIdx.x * 256 + tid;
    if (tid < TN) tbS[tid] = tboxes[b * TN + tid];
    __syncthreads();
    float4 ab = anchors[a];
    float a1 = (ab.z - ab.x) * (ab.w - ab.y);
    float best = -1.0f; int bt = 0;
#pragma unroll
    for (int t = 0; t < TN; ++t) {
        float4 t4 = tbS[t];
        float x1 = fmaxf(ab.x, t4.x), y1 = fmaxf(ab.y, t4.y);
        float x2 = fminf(ab.z, t4.z), y2 = fminf(ab.w, t4.w);
        float inter = fmaxf(x2 - x1, 0.f) * fmaxf(y2 - y1, 0.f);
        float a2 = (t4.z - t4.x) * (t4.w - t4.y);
        float iou = inter / (a1 + a2 - inter + 1e-6f);
        iouS[tid * (TN + 1) + t] = iou;
        if (iou > best) { best = iou; bt = t; }
    }
    max_iou[(size_t)b * AN + a] = best;
    best_t[(size_t)b * AN + a] = (unsigned char)bt;
    __syncthreads();
    {
        int t = tid >> 3, pp = tid & 7;
        float bv = -1.f; int ba = 0;
        for (int r = pp * 32; r < pp * 32 + 32; ++r) {
            float v = iouS[r * (TN + 1) + t];
            if (v > bv) { bv = v; ba = r; }
        }
        pbV[t][pp] = bv; pbA[t][pp] = ba;
    }
    __syncthreads();
    if (tid < TN) {
        float bv = -1.f; int ba = 0;
#pragma unroll
        for (int pp = 0; pp < 8; ++pp) {
            float v = pbV[tid][pp];
            if (v > bv) { bv = v; ba = pbA[tid][pp]; }
        }
        unsigned ga = blockIdx.x * 256 + (unsigned)ba;
        unsigned long long key =
            (((unsigned long long)__float_as_uint(bv)) << 32) | (unsigned long long)(unsigned)(~ga);
        atomicMax(&gbest[b * TN + tid], key);
    }
}

// ---------- kernel B: force-match overrides ----------
__global__ void force_kernel(const unsigned long long* __restrict__ gbest,
                             unsigned char* __restrict__ ovr)
{
    int i = blockIdx.x * blockDim.x + threadIdx.x;
    if (i < BN * TN) {
        unsigned long long key = gbest[i];
        unsigned ga = ~(unsigned)(key & 0xFFFFFFFFull);
        int b = i / TN;
        ovr[(size_t)b * AN + ga] = 1;
    }
}

// ---------- kernel C: focal, sums, anchor-max bits + 512-bin anchor hist ----------
__global__ __launch_bounds__(256) void main_kernel(
    const float* __restrict__ conf, const float4* __restrict__ bboxp,
    const float4* __restrict__ tboxes, const int* __restrict__ tlabels,
    const float* __restrict__ max_iou, const unsigned char* __restrict__ best_t,
    const unsigned char* __restrict__ ovr,
    unsigned* __restrict__ ahist, unsigned* __restrict__ maxb,
    Accum* __restrict__ acc)
{
    __shared__ float confS[256 * CN];        // 21504 B
    __shared__ unsigned ah[NBA];             // 2048 B
    __shared__ float4 tbS[TN];
    __shared__ int tlS[TN];
    __shared__ float rF[3][4];
    __shared__ int rI[2][4];
    int b = blockIdx.y, tid = threadIdx.x;
    int a = blockIdx.x * 256 + tid;
    for (int i = tid; i < NBA; i += 256) ah[i] = 0u;
    if (tid < TN) { tbS[tid] = tboxes[b * TN + tid]; tlS[tid] = tlabels[b * TN + tid]; }
    {
        const float4* cp = (const float4*)(conf + ((size_t)b * AN + (size_t)blockIdx.x * 256) * CN);
        float4* cs = (float4*)confS;
        for (int i = tid; i < (256 * CN) / 4; i += 256) cs[i] = cp[i];
    }
    __syncthreads();

    size_t idx = (size_t)b * AN + a;
    float mi = max_iou[idx];
    bool ov = ovr[idx] != 0;
    bool posA = (mi >= 0.5f) || ov;
    bool negA = (mi < 0.4f) && !ov;
    int bt = best_t[idx];
    int label = posA ? tlS[bt] : -1;

    float p[CN];
    softmax_row(&confS[tid * CN], p);
    float fall = 0.f;
    unsigned mb = 0u;
#pragma unroll
    for (int j = 0; j < CN; ++j) {
        float fo = focal_cell(p[j], j == label);
        fall += fo;
        mb = max(mb, focal_bits(fo));
    }
    maxb[idx] = negA ? mb : 0u;
    if (negA) atomicAdd(&ah[mb >> 22], 1u);   // one LDS atomic per neg anchor

    float bper = 0.f;
    if (posA) {
        float4 b1 = bboxp[idx];
        float4 b2 = tbS[bt];
        float x1 = fmaxf(b1.x, b2.x), y1 = fmaxf(b1.y, b2.y);
        float x2 = fminf(b1.z, b2.z), y2 = fminf(b1.w, b2.w);
        float inter = fmaxf(x2 - x1, 0.f) * fmaxf(y2 - y1, 0.f);
        float a1 = (b1.z - b1.x) * (b1.w - b1.y);
        float a2 = (b2.z - b2.x) * (b2.w - b2.y);
        float un = a1 + a2 - inter;
        float iou = inter / (un + 1e-6f);
        float ex1 = fminf(b1.x, b2.x), ey1 = fminf(b1.y, b2.y);
        float ex2 = fmaxf(b1.z, b2.z), ey2 = fmaxf(b1.w, b2.w);
        float enc = (ex2 - ex1) * (ey2 - ey1);
        float giou = iou - (enc - un) / (enc + 1e-6f);
        float gl = 1.0f - giou;
        float l1 = 0.f, d, ad;
        d = b1.x - b2.x; ad = fabsf(d); l1 += (ad < 1.0f) ? (0.5f * d * d) : (ad - 0.5f);
        d = b1.y - b2.y; ad = fabsf(d); l1 += (ad < 1.0f) ? (0.5f * d * d) : (ad - 0.5f);
        d = b1.z - b2.z; ad = fabsf(d); l1 += (ad < 1.0f) ? (0.5f * d * d) : (ad - 0.5f);
        d = b1.w - b2.w; ad = fabsf(d); l1 += (ad < 1.0f) ? (0.5f * d * d) : (ad - 0.5f);
        l1 *= 0.25f;
        bper = gl + 0.5f * l1;
    }
    float vall = fall, vpos = posA ? fall : 0.f, vb = bper;
    int inp = posA ? 1 : 0, inn = negA ? 1 : 0;
#pragma unroll
    for (int off = 32; off; off >>= 1) {
        vall += __shfl_down(vall, off, 64);
        vpos += __shfl_down(vpos, off, 64);
        vb   += __shfl_down(vb,   off, 64);
        inp  += __shfl_down(inp,  off, 64);
        inn  += __shfl_down(inn,  off, 64);
    }
    int wv = tid >> 6, ln = tid & 63;
    if (ln == 0) { rF[0][wv] = vall; rF[1][wv] = vpos; rF[2][wv] = vb; rI[0][wv] = inp; rI[1][wv] = inn; }
    __syncthreads();
    if (tid == 0) {
        float s0 = 0, s1 = 0, s2 = 0; int c0 = 0, c1 = 0;
        for (int w = 0; w < 4; ++w) { s0 += rF[0][w]; s1 += rF[1][w]; s2 += rF[2][w]; c0 += rI[0][w]; c1 += rI[1][w]; }
        atomicAdd(&acc[b].all_sum, (double)s0);
        atomicAdd(&acc[b].pos_sum, (double)s1);
        atomicAdd(&acc[b].bbox_sum, (double)s2);
        atomicAdd(&acc[b].num_pos, (unsigned)c0);
        atomicAdd(&acc[b].n_neg, (unsigned)c1);
    }
    for (int i = tid; i < NBA; i += 256) {
        unsigned v = ah[i];
        if (v) atomicAdd(&ahist[b * NBA + i], v);
    }
}

// ---------- select0: anchor-max threshold bin ----------
__global__ __launch_bounds__(128) void select0_kernel(
    const unsigned* __restrict__ ahist, const Accum* __restrict__ acc,
    Chain* __restrict__ chains)
{
    int b = blockIdx.x, tid = threadIdx.x;   // 128 threads x 4 bins
    Chain* ch = &chains[b];
    unsigned np = acc[b].num_pos, nn = acc[b].n_neg;
    unsigned k = (np > 0) ? min(3u * np, nn) : min(100u, nn);
    if (nn == 0 || k == 0) return;           // inactive; topk stays 0
    const unsigned* h = ahist + b * NBA;
    unsigned lc[4], ccnt = 0;
#pragma unroll
    for (int i = 0; i < 4; ++i) { lc[i] = h[tid * 4 + i]; ccnt += lc[i]; }
    __shared__ unsigned scnt[128];
    scnt[tid] = ccnt;
    __syncthreads();
    for (int off = 1; off < 128; off <<= 1) {
        unsigned vc = (tid + off < 128) ? scnt[tid + off] : 0u;
        __syncthreads();
        scnt[tid] += vc;
        __syncthreads();
    }
    unsigned aboveCnt = (tid < 127) ? scnt[tid + 1] : 0u;
    if (aboveCnt < k && aboveCnt + ccnt >= k) {
        unsigned acc2 = aboveCnt;
        for (int i = 3; i >= 0; --i) {
            if (acc2 + lc[i] >= k) {
                ch->active = 1;
                ch->k = k;
                ch->vbits = (unsigned)(tid * 4 + i) << 22;
                break;
            }
            acc2 += lc[i];
        }
    }
}

// ---------- collect: candidate anchors + exact cell hist over cells >= v ----------
__global__ __launch_bounds__(256) void collect_kernel(
    const float* __restrict__ conf, const float* __restrict__ max_iou,
    const unsigned char* __restrict__ ovr, const unsigned* __restrict__ maxb,
    const Chain* __restrict__ chains,
    int* __restrict__ cand, unsigned* __restrict__ cand_cnt,
    unsigned* __restrict__ cnt1)
{
    int b = blockIdx.y;
    const Chain* ch = &chains[b];
    if (!ch->active) return;
    unsigned v = ch->vbits;
    int a = blockIdx.x * 256 + threadIdx.x;
    size_t idx = (size_t)b * AN + a;
    unsigned mb = maxb[idx];
    float mi = max_iou[idx];
    if (!((mi < 0.4f) && (ovr[idx] == 0) && (mb >= v))) return;
    unsigned pos = atomicAdd(&cand_cnt[b], 1u);
    cand[b * AN + pos] = a;
    float p[CN];
    softmax_row(conf + idx * CN, p);
#pragma unroll
    for (int j = 0; j < CN; ++j) {
        float fo = focal_cell(p[j], false);
        unsigned bits = focal_bits(fo);
        if (bits >= v) atomicAdd(&cnt1[b * NB1 + (bits >> 20)], 1u);
    }
}

// ---------- select level 1 (cell counts) ----------
__global__ __launch_bounds__(256) void select1_kernel(
    const unsigned* __restrict__ cnt1, Chain* __restrict__ chains)
{
    int b = blockIdx.x, tid = threadIdx.x;
    Chain* ch = &chains[b];
    if (!ch->active) return;
    unsigned k = ch->k;
    const unsigned* cnt = cnt1 + (size_t)b * NB1;
    unsigned lc[16], ccnt = 0;
#pragma unroll
    for (int i = 0; i < 16; ++i) { lc[i] = cnt[tid * 16 + i]; ccnt += lc[i]; }
    __shared__ unsigned scnt[256];
    scnt[tid] = ccnt;
    __syncthreads();
    for (int off = 1; off < 256; off <<= 1) {
        unsigned vc = (tid + off < 256) ? scnt[tid + off] : 0u;
        __syncthreads();
        scnt[tid] += vc;
        __syncthreads();
    }
    unsigned total = scnt[0];
    unsigned aboveCnt = (tid < 255) ? scnt[tid + 1] : 0u;
    unsigned r = min(k, total);
    if (r == 0) return;
    if (aboveCnt < r && aboveCnt + ccnt >= r) {
        unsigned acc2 = aboveCnt;
        for (int i = 15; i >= 0; --i) {
            unsigned bc = lc[i];
            if (acc2 + bc >= r) { ch->b1 = (unsigned)(tid * 16 + i); ch->rem = r - acc2; break; }
            acc2 += bc;
        }
    }
}

// ---------- refine level 2 over candidates ----------
__global__ __launch_bounds__(256) void refine2_kernel(
    const float* __restrict__ conf, const int* __restrict__ cand,
    const unsigned* __restrict__ cand_cnt, Chain* __restrict__ chains,
    unsigned* __restrict__ cnt2, double* __restrict__ sum2)
{
    int b = blockIdx.y;
    Chain* ch = &chains[b];
    if (!ch->active) return;
    unsigned m = cand_cnt[b];
    unsigned i = blockIdx.x * 256 + threadIdx.x;
    if (i >= m) return;
    int a = cand[b * AN + i];
    unsigned b1 = ch->b1;
    size_t idx = (size_t)b * AN + a;
    float p[CN];
    softmax_row(conf + idx * CN, p);
    double sA = 0.0;
#pragma unroll
    for (int j = 0; j < CN; ++j) {
        float fo = focal_cell(p[j], false);
        unsigned bits = focal_bits(fo);
        unsigned hi = bits >> 20;
        if (hi > b1) sA += (double)fo;
        else if (hi == b1) {
            unsigned bin = (bits >> 8) & 0xFFFu;
            atomicAdd(&cnt2[b * NB1 + bin], 1u);
            atomicAdd(&sum2[b * NB1 + bin], (double)fo);
        }
    }
    if (sA != 0.0) atomicAdd(&ch->sumAbove, sA);
}

// ---------- select level 2 ----------
__global__ __launch_bounds__(256) void select2_kernel(
    const unsigned* __restrict__ cnt2, const double* __restrict__ sum2,
    Chain* __restrict__ chains)
{
    int b = blockIdx.x, tid = threadIdx.x;
    Chain* ch = &chains[b];
    if (!ch->active) return;
    unsigned rem = ch->rem;
    const unsigned* cnt = cnt2 + (size_t)b * NB1;
    const double* sum = sum2 + (size_t)b * NB1;
    unsigned lc[16], ccnt = 0; double ls[16], csum = 0.0;
#pragma unroll
    for (int i = 0; i < 16; ++i) {
        lc[i] = cnt[tid * 16 + i]; ls[i] = sum[tid * 16 + i];
        ccnt += lc[i]; csum += ls[i];
    }
    __shared__ unsigned scnt[256];
    __shared__ double ssum[256];
    scnt[tid] = ccnt; ssum[tid] = csum;
    __syncthreads();
    for (int off = 1; off < 256; off <<= 1) {
        unsigned vc = 0; double vs = 0.0;
        if (tid + off < 256) { vc = scnt[tid + off]; vs = ssum[tid + off]; }
        __syncthreads();
        scnt[tid] += vc; ssum[tid] += vs;
        __syncthreads();
    }
    unsigned total = scnt[0];
    unsigned aboveCnt = (tid < 255) ? scnt[tid + 1] : 0u;
    double aboveSum = (tid < 255) ? ssum[tid + 1] : 0.0;
    unsigned r = min(rem, total);
    if (r == 0) return;
    if (aboveCnt < r && aboveCnt + ccnt >= r) {
        unsigned acc2 = aboveCnt; double asum = aboveSum;
        for (int i = 15; i >= 0; --i) {
            unsigned bc = lc[i];
            if (acc2 + bc >= r) {
                ch->b2 = (unsigned)(tid * 16 + i);
                ch->rem = r - acc2;
                ch->sumAbove += asum;
                break;
            }
            acc2 += bc; asum += ls[i];
        }
    }
}

// ---------- refine level 3 over candidates ----------
__global__ __launch_bounds__(256) void refine3_kernel(
    const float* __restrict__ conf, const int* __restrict__ cand,
    const unsigned* __restrict__ cand_cnt, const Chain* __restrict__ chains,
    unsigned* __restrict__ cnt3, double* __restrict__ sum3)
{
    int b = blockIdx.y;
    const Chain* ch = &chains[b];
    if (!ch->active) return;
    unsigned m = cand_cnt[b];
    unsigned i = blockIdx.x * 256 + threadIdx.x;
    if (i >= m) return;
    int a = cand[b * AN + i];
    unsigned hi24 = (ch->b1 << 12) | ch->b2;
    size_t idx = (size_t)b * AN + a;
    float p[CN];
    softmax_row(conf + idx * CN, p);
#pragma unroll
    for (int j = 0; j < CN; ++j) {
        float fo = focal_cell(p[j], false);
        unsigned bits = focal_bits(fo);
        if ((bits >> 8) == hi24) {
            unsigned bin = bits & 0xFFu;
            atomicAdd(&cnt3[b * 256 + bin], 1u);
            atomicAdd(&sum3[b * 256 + bin], (double)fo);
        }
    }
}

// ---------- select level 3 (final) ----------
__global__ __launch_bounds__(256) void select3_kernel(
    const unsigned* __restrict__ cnt3, const double* __restrict__ sum3,
    Chain* __restrict__ chains)
{
    int b = blockIdx.x, tid = threadIdx.x;
    Chain* ch = &chains[b];
    if (!ch->active) return;
    unsigned rem = ch->rem;
    unsigned c = cnt3[b * 256 + tid];
    double s = sum3[b * 256 + tid];
    __shared__ unsigned scnt[256];
    __shared__ double ssum[256];
    scnt[tid] = c; ssum[tid] = s;
    __syncthreads();
    for (int off = 1; off < 256; off <<= 1) {
        unsigned vc = 0; double vs = 0.0;
        if (tid + off < 256) { vc = scnt[tid + off]; vs = ssum[tid + off]; }
        __syncthreads();
        scnt[tid] += vc; ssum[tid] += vs;
        __syncthreads();
    }
    unsigned total = scnt[0];
    unsigned aboveCnt = (tid < 255) ? scnt[tid + 1] : 0u;
    double aboveSum = (tid < 255) ? ssum[tid + 1] : 0.0;
    unsigned r = min(rem, total);
    if (r == 0) { if (tid == 0) ch->topk = ch->sumAbove; return; }
    if (aboveCnt < r && aboveCnt + c >= r) {
        unsigned vbits = (ch->b1 << 20) | (ch->b2 << 8) | (unsigned)tid;
        double v = (double)__uint_as_float(vbits);
        ch->topk = ch->sumAbove + aboveSum + (double)(r - aboveCnt) * v;
    }
}

// ---------- finalize ----------
__global__ void finalize_kernel(const Accum* __restrict__ acc,
                                const Chain* __restrict__ chains,
                                float* __restrict__ out)
{
    __shared__ double cl[BN], bl[BN];
    int t = threadIdx.x;
    if (t < BN) {
        unsigned np = acc[t].num_pos, nn = acc[t].n_neg;
        double pos_sum = acc[t].pos_sum, all_sum = acc[t].all_sum, bbox_sum = acc[t].bbox_sum;
        double conf;
        if (np > 0) {
            if (nn > 0) {
                unsigned k = min(3u * np, nn);
                conf = (pos_sum + chains[t].topk) / (double)(np + k);
            } else conf = pos_sum / (double)np;
        } else {
            if (nn > 0) {
                unsigned k2 = min(100u, nn);
                conf = chains[t].topk / (double)(k2 > 0 ? k2 : 1u);
            } else conf = all_sum / (double)((size_t)AN * CN);
        }
        cl[t] = conf;
        bl[t] = (np > 0) ? (bbox_sum / (double)np) : 0.0;
    }
    __syncthreads();
    if (t == 0) {
        double cs = 0, bs = 0;
        for (int i = 0; i < BN; ++i) { cs += cl[i]; bs += bl[i]; }
        cs /= BN; bs /= BN;
        out[0] = (float)(cs + bs);
        out[1] = (float)cs;
        out[2] = (float)bs;
    }
}

extern "C" void kernel_launch(void* const* d_in, const int* in_sizes, int n_in,
                              void* d_out, int out_size, void* d_ws, size_t ws_size,
                              hipStream_t stream)
{
    (void)in_sizes; (void)n_in; (void)out_size; (void)ws_size;
    const float*  conf    = (const float*)d_in[0];
    const float4* bboxp   = (const float4*)d_in[1];
    const float4* anchors = (const float4*)d_in[2];
    const float4* tboxes  = (const float4*)d_in[3];
    const int*    tlabels = (const int*)d_in[4];
    float* out = (float*)d_out;
    char* ws = (char*)d_ws;
    size_t off = 0;
    auto alloc = [&](size_t bytes) -> void* {
        void* p = (void*)(ws + off);
        off = (off + bytes + 255) & ~(size_t)255;
        return p;
    };
    float*              max_iou = (float*)alloc((size_t)BN * AN * 4);
    unsigned char*      bestt   = (unsigned char*)alloc((size_t)BN * AN);
    unsigned*           maxb    = (unsigned*)alloc((size_t)BN * AN * 4);
    int*                cand    = (int*)alloc((size_t)BN * AN * 4);
    size_t zstart = off;
    unsigned char*      ovr    = (unsigned char*)alloc((size_t)BN * AN);
    unsigned long long* gbest  = (unsigned long long*)alloc((size_t)BN * TN * 8);
    Accum*              acc    = (Accum*)alloc(BN * sizeof(Accum));
    Chain*              chains = (Chain*)alloc(BN * sizeof(Chain));
    unsigned* ahist    = (unsigned*)alloc((size_t)BN * NBA * 4);
    unsigned* cand_cnt = (unsigned*)alloc((size_t)BN * 4);
    unsigned* cnt1 = (unsigned*)alloc((size_t)BN * NB1 * 4);
    unsigned* cnt2 = (unsigned*)alloc((size_t)BN * NB1 * 4);
    double*   sum2 = (double*)alloc((size_t)BN * NB1 * 8);
    unsigned* cnt3 = (unsigned*)alloc((size_t)BN * 256 * 4);
    double*   sum3 = (double*)alloc((size_t)BN * 256 * 8);
    size_t zbytes = off - zstart;
    hipMemsetAsync(ws + zstart, 0, zbytes, stream);

    dim3 gridA(AN / 256, BN);
    match_kernel<<<gridA, 256, 0, stream>>>(anchors, tboxes, max_iou, bestt, gbest);
    force_kernel<<<1, 512, 0, stream>>>(gbest, ovr);
    main_kernel<<<gridA, 256, 0, stream>>>(conf, bboxp, tboxes, tlabels, max_iou, bestt, ovr,
                                           ahist, maxb, acc);
    select0_kernel<<<BN, 128, 0, stream>>>(ahist, acc, chains);
    collect_kernel<<<gridA, 256, 0, stream>>>(conf, max_iou, ovr, maxb, chains, cand, cand_cnt, cnt1);
    select1_kernel<<<BN, 256, 0, stream>>>(cnt1, chains);
    refine2_kernel<<<gridA, 256, 0, stream>>>(conf, cand, cand_cnt, chains, cnt2, sum2);
    select2_kernel<<<BN, 256, 0, stream>>>(cnt2, sum2, chains);
    refine3_kernel<<<gridA, 256, 0, stream>>>(conf, cand, cand_cnt, chains, cnt3, sum3);
    select3_kernel<<<BN, 256, 0, stream>>>(cnt3, sum3, chains);
    finalize_kernel<<<1, 64, 0, stream>>>(acc, chains, out);
}

// Round 4
// 425.004 us; speedup vs baseline: 1.2527x; 1.2527x over previous
//
#include <hip/hip_runtime.h>

// DetectionLoss: B=16, A=65536, T=32, C=21.
// R4: fused match+focal main (recompute-based per-target argmax, 15KB LDS,
// blockAcc plain stores); force-match handled by tiny post-fix kernel
// (num_pos>=1 always => no all_sum / no q-chain). 2048-bin anchor-max
// histogram -> tight threshold; wave-aggregated candidate compaction;
// 3-level radix select (11/12/8 bits) over candidates only.

#define AN 65536
#define BN 16
#define TN 32
#define CN 21
#define NBA 2048   // bits>>20 of positive float in [0,2047]
#define NB2 4096
#define NB3 256

struct Acc   { double pos_sum; double bbox_sum; unsigned np; unsigned nn; };
struct Delta { double dpos; double dbbox; int dnp; int dnn; };
struct Chain { double sumAbove; double topk; unsigned active; unsigned k; unsigned ve;
               unsigned b1; unsigned b2; unsigned rem; };
struct BlockAcc { float pos_sum; float bbox_sum; unsigned np; unsigned nn; };

// ---------- shared math: bit-identical across kernels (_rn intrinsics) ----------
__device__ __forceinline__ float row_prep(const float* __restrict__ row, float* __restrict__ c) {
#pragma unroll
    for (int j = 0; j < CN; ++j) c[j] = row[j];
    float m = c[0];
#pragma unroll
    for (int j = 1; j < CN; ++j) m = fmaxf(m, c[j]);
    float s = 0.f;
#pragma unroll
    for (int j = 0; j < CN; ++j) { c[j] = __expf(__fsub_rn(c[j], m)); s = __fadd_rn(s, c[j]); }
    return 1.0f / s;
}
__device__ __forceinline__ float cell_focal(float cexp, float inv, bool cellpos) {
    float p = __fmul_rn(cexp, inv);
    float pt = cellpos ? p : __fsub_rn(1.0f, p);
    float af = cellpos ? 0.25f : 0.75f;
    float om = __fsub_rn(1.0f, pt);
    float lg = __logf(fmaxf(pt, 1e-6f));
    return __fmul_rn(__fmul_rn(__fmul_rn(-af, om), om), lg);
}
__device__ __forceinline__ unsigned focal_bits(float fo) {
    unsigned bits = __float_as_uint(fo);
    if (bits == 0x80000000u) bits = 0u;   // canonicalize -0.0
    return bits;
}
// (anchor, anchorArea, target, targetArea) — fixed op order for bit-identical recompute
__device__ __forceinline__ float iou_pair(float4 A, float aa, float4 T, float ta) {
    float x1 = fmaxf(A.x, T.x), y1 = fmaxf(A.y, T.y);
    float x2 = fminf(A.z, T.z), y2 = fminf(A.w, T.w);
    float inter = fmaxf(x2 - x1, 0.f) * fmaxf(y2 - y1, 0.f);
    return inter / (aa + ta - inter + 1e-6f);
}
__device__ __forceinline__ float bbox_per(float4 b1, float4 b2) {
    float x1 = fmaxf(b1.x, b2.x), y1 = fmaxf(b1.y, b2.y);
    float x2 = fminf(b1.z, b2.z), y2 = fminf(b1.w, b2.w);
    float inter = fmaxf(x2 - x1, 0.f) * fmaxf(y2 - y1, 0.f);
    float a1 = (b1.z - b1.x) * (b1.w - b1.y);
    float a2 = (b2.z - b2.x) * (b2.w - b2.y);
    float un = a1 + a2 - inter;
    float iou = inter / (un + 1e-6f);
    float ex1 = fminf(b1.x, b2.x), ey1 = fminf(b1.y, b2.y);
    float ex2 = fmaxf(b1.z, b2.z), ey2 = fmaxf(b1.w, b2.w);
    float enc = (ex2 - ex1) * (ey2 - ey1);
    float giou = iou - (enc - un) / (enc + 1e-6f);
    float gl = 1.0f - giou;
    float l1 = 0.f, d, ad;
    d = b1.x - b2.x; ad = fabsf(d); l1 += (ad < 1.f) ? (0.5f * d * d) : (ad - 0.5f);
    d = b1.y - b2.y; ad = fabsf(d); l1 += (ad < 1.f) ? (0.5f * d * d) : (ad - 0.5f);
    d = b1.z - b2.z; ad = fabsf(d); l1 += (ad < 1.f) ? (0.5f * d * d) : (ad - 0.5f);
    d = b1.w - b2.w; ad = fabsf(d); l1 += (ad < 1.f) ? (0.5f * d * d) : (ad - 0.5f);
    return gl + 0.5f * (l1 * 0.25f);
}

// ---------- fused main: match + force-argmax + focal + anchor hist ----------
__global__ __launch_bounds__(256) void main_kernel(
    const float* __restrict__ conf, const float4* __restrict__ bboxp,
    const float4* __restrict__ anchors, const float4* __restrict__ tboxes,
    const int* __restrict__ tlabels,
    float* __restrict__ max_iou, unsigned char* __restrict__ best_t,
    unsigned long long* __restrict__ gbest,
    unsigned* __restrict__ ahist, unsigned* __restrict__ maxb,
    BlockAcc* __restrict__ blockAcc)
{
    __shared__ float4 tbS[TN];
    __shared__ float4 aS[256];
    __shared__ int tlS[TN];
    __shared__ unsigned ah[NBA];           // 8 KB
    __shared__ float pbV[TN][8];
    __shared__ int   pbA[TN][8];
    __shared__ float rF[2][4];
    __shared__ unsigned rI[2][4];
    int b = blockIdx.y, tid = threadIdx.x;
    int a = blockIdx.x * 256 + tid;
    for (int i = tid; i < NBA; i += 256) ah[i] = 0u;
    if (tid < TN) { tbS[tid] = tboxes[b * TN + tid]; tlS[tid] = tlabels[b * TN + tid]; }
    float4 ab = anchors[a];
    aS[tid] = ab;
    __syncthreads();

    // phase 1: per-anchor max IoU over targets
    float a1 = (ab.z - ab.x) * (ab.w - ab.y);
    float best = -1.0f; int bt = 0;
#pragma unroll
    for (int t = 0; t < TN; ++t) {
        float4 T = tbS[t];
        float ta = (T.z - T.x) * (T.w - T.y);
        float iou = iou_pair(ab, a1, T, ta);
        if (iou > best) { best = iou; bt = t; }   // strict >: first-occurrence argmax
    }
    size_t idx = (size_t)b * AN + a;
    max_iou[idx] = best;
    best_t[idx] = (unsigned char)bt;

    // phase 2: per-target best anchor within block (recompute from LDS)
    {
        int t = tid & 31, pp = tid >> 5;
        float4 T = tbS[t];
        float ta = (T.z - T.x) * (T.w - T.y);
        float bv = -1.f; int ba = 0;
        for (int r = pp * 32; r < pp * 32 + 32; ++r) {
            float4 A = aS[r];
            float aa = (A.z - A.x) * (A.w - A.y);
            float iou = iou_pair(A, aa, T, ta);
            if (iou > bv) { bv = iou; ba = r; }
        }
        pbV[t][pp] = bv; pbA[t][pp] = ba;
    }
    __syncthreads();
    if (tid < TN) {
        float bv = -1.f; int ba = 0;
#pragma unroll
        for (int pp = 0; pp < 8; ++pp) {
            float v = pbV[tid][pp];
            if (v > bv) { bv = v; ba = pbA[tid][pp]; }
        }
        unsigned ga = blockIdx.x * 256 + (unsigned)ba;
        unsigned long long key =
            (((unsigned long long)__float_as_uint(bv)) << 32) | (unsigned long long)(unsigned)(~ga);
        atomicMax(&gbest[b * TN + tid], key);   // tie -> smaller anchor idx
    }

    // phase 3: focal (threshold classification only; forced anchors fixed later)
    bool posA = best >= 0.5f;
    bool negA = best < 0.4f;
    float fs = 0.f, bper = 0.f;
    unsigned mbenc = 0u;
    if (posA || negA) {
        int label = posA ? tlS[bt] : -1;
        float c[CN];
        float inv = row_prep(conf + idx * CN, c);
        unsigned mb = 0u;
#pragma unroll
        for (int j = 0; j < CN; ++j) {
            float fo = cell_focal(c[j], inv, j == label);
            fs += fo;
            mb = max(mb, focal_bits(fo));
        }
        if (negA) { mbenc = (mb << 1) | 1u; atomicAdd(&ah[mb >> 20], 1u); fs = 0.f; }
        else      { bper = bbox_per(bboxp[idx], tbS[bt]); }
    }
    maxb[idx] = mbenc;

    // block reduce {pos_sum, bbox_sum, np, nn} -> plain store (no global atomics)
    float vpos = fs, vb = bper;
    unsigned inp = posA ? 1u : 0u, inn = negA ? 1u : 0u;
#pragma unroll
    for (int off = 32; off; off >>= 1) {
        vpos += __shfl_down(vpos, off, 64);
        vb   += __shfl_down(vb,   off, 64);
        inp  += __shfl_down(inp,  off, 64);
        inn  += __shfl_down(inn,  off, 64);
    }
    int wv = tid >> 6, ln = tid & 63;
    if (ln == 0) { rF[0][wv] = vpos; rF[1][wv] = vb; rI[0][wv] = inp; rI[1][wv] = inn; }
    __syncthreads();
    if (tid == 0) {
        BlockAcc ba2;
        ba2.pos_sum = rF[0][0] + rF[0][1] + rF[0][2] + rF[0][3];
        ba2.bbox_sum = rF[1][0] + rF[1][1] + rF[1][2] + rF[1][3];
        ba2.np = rI[0][0] + rI[0][1] + rI[0][2] + rI[0][3];
        ba2.nn = rI[1][0] + rI[1][1] + rI[1][2] + rI[1][3];
        blockAcc[b * 256 + blockIdx.x] = ba2;
    }
    // flush anchor histogram
    for (int i = tid; i < NBA; i += 256) {
        unsigned v = ah[i];
        if (v) atomicAdd(&ahist[b * NBA + i], v);
    }
}

// ---------- force-match fix: <=32 anchors/image ----------
__global__ void force_fix_kernel(
    const float* __restrict__ conf, const float4* __restrict__ bboxp,
    const float4* __restrict__ tboxes, const int* __restrict__ tlabels,
    const float* __restrict__ max_iou, const unsigned char* __restrict__ best_t,
    const unsigned long long* __restrict__ gbest,
    unsigned* __restrict__ ahist, unsigned* __restrict__ maxb,
    Delta* __restrict__ delta)
{
    __shared__ unsigned gaS[TN];
    __shared__ float4 tbS[TN];
    __shared__ int tlS[TN];
    int b = blockIdx.x, t = threadIdx.x;
    if (t < TN) {
        gaS[t] = ~(unsigned)(gbest[b * TN + t] & 0xFFFFFFFFull);
        tbS[t] = tboxes[b * TN + t];
        tlS[t] = tlabels[b * TN + t];
    }
    __syncthreads();
    if (t >= TN) return;
    unsigned ga = gaS[t];
    for (int u = 0; u < t; ++u) if (gaS[u] == ga) return;   // dedupe (idempotent .set)
    size_t idx = (size_t)b * AN + ga;
    float mi = max_iou[idx];
    if (mi >= 0.5f) return;   // already pos via threshold
    int bt = best_t[idx];
    int label = tlS[bt];
    float c[CN];
    float inv = row_prep(conf + idx * CN, c);
    float fs = 0.f;
#pragma unroll
    for (int j = 0; j < CN; ++j) fs += cell_focal(c[j], inv, j == label);
    float bper = bbox_per(bboxp[idx], tbS[bt]);
    atomicAdd(&delta[b].dpos, (double)fs);
    atomicAdd(&delta[b].dbbox, (double)bper);
    atomicAdd(&delta[b].dnp, 1);
    if (mi < 0.4f) {   // was counted neg: undo
        unsigned mb = maxb[idx];
        atomicSub(&ahist[b * NBA + (mb >> 21)], 1u);
        maxb[idx] = 0u;
        atomicAdd(&delta[b].dnn, -1);
    }
}

// ---------- select0: totals + anchor-max threshold ----------
__global__ __launch_bounds__(256) void select0_kernel(
    const BlockAcc* __restrict__ blockAcc, const Delta* __restrict__ delta,
    const unsigned* __restrict__ ahist, Acc* __restrict__ acc,
    Chain* __restrict__ chains)
{
    int b = blockIdx.x, tid = threadIdx.x;
    BlockAcc ba = blockAcc[b * 256 + tid];
    double ps = (double)ba.pos_sum, bs = (double)ba.bbox_sum;
    unsigned np = ba.np, nn = ba.nn;
#pragma unroll
    for (int off = 32; off; off >>= 1) {
        ps += __shfl_down(ps, off, 64);
        bs += __shfl_down(bs, off, 64);
        np += __shfl_down(np, off, 64);
        nn += __shfl_down(nn, off, 64);
    }
    __shared__ double sps[4], sbs[4];
    __shared__ unsigned snp[4], snn[4];
    __shared__ unsigned s_np, s_nn;
    int wv = tid >> 6, ln = tid & 63;
    if (ln == 0) { sps[wv] = ps; sbs[wv] = bs; snp[wv] = np; snn[wv] = nn; }
    __syncthreads();
    if (tid == 0) {
        Acc A;
        A.pos_sum = sps[0] + sps[1] + sps[2] + sps[3] + delta[b].dpos;
        A.bbox_sum = sbs[0] + sbs[1] + sbs[2] + sbs[3] + delta[b].dbbox;
        A.np = (unsigned)((int)(snp[0] + snp[1] + snp[2] + snp[3]) + delta[b].dnp);
        A.nn = (unsigned)((int)(snn[0] + snn[1] + snn[2] + snn[3]) + delta[b].dnn);
        acc[b] = A;
        s_np = A.np; s_nn = A.nn;
    }
    __syncthreads();
    unsigned npT = s_np, nnT = s_nn;
    if (nnT == 0) return;   // chain inactive; finalize uses pos-only branch
    unsigned k = min(3u * npT, nnT);
    const unsigned* h = ahist + b * NBA;
    unsigned lc[8], ccnt = 0;
#pragma unroll
    for (int i = 0; i < 8; ++i) { lc[i] = h[tid * 8 + i]; ccnt += lc[i]; }
    __shared__ unsigned scnt[256];
    scnt[tid] = ccnt;
    __syncthreads();
    for (int off = 1; off < 256; off <<= 1) {
        unsigned vc = (tid + off < 256) ? scnt[tid + off] : 0u;
        __syncthreads();
        scnt[tid] += vc;
        __syncthreads();
    }
    unsigned aboveCnt = (tid < 255) ? scnt[tid + 1] : 0u;
    if (aboveCnt < k && aboveCnt + ccnt >= k) {
        unsigned acc2 = aboveCnt;
        for (int i = 7; i >= 0; --i) {
            if (acc2 + lc[i] >= k) {
                unsigned bin = (unsigned)(tid * 8 + i);
                chains[b].active = 1;
                chains[b].k = k;
                chains[b].ve = (bin << 21) | 1u;   // encoded threshold
                break;
            }
            acc2 += lc[i];
        }
    }
}

// ---------- collect: compact candidates + L1 cell hist ----------
__global__ __launch_bounds__(256) void collect_kernel(
    const float* __restrict__ conf, const unsigned* __restrict__ maxb,
    const Chain* __restrict__ chains,
    int* __restrict__ cand, unsigned* __restrict__ cand_cnt,
    unsigned* __restrict__ cnt1)
{
    int b = blockIdx.y;
    if (!chains[b].active) return;
    unsigned ve = chains[b].ve;
    int tid = threadIdx.x;
    int a = blockIdx.x * 256 + tid;
    size_t idx = (size_t)b * AN + a;
    unsigned mb = maxb[idx];          // 0 for non-neg; (bits<<1)|1 for neg
    bool q = (mb >= ve);
    int total = __syncthreads_count(q ? 1 : 0);
    if (total == 0) return;
    __shared__ unsigned h[NBA];
    for (int i = tid; i < NBA; i += 256) h[i] = 0u;
    __syncthreads();
    if (q) {
        unsigned long long msk = __ballot(1);   // exec mask == q-lanes
        unsigned pre = __builtin_amdgcn_mbcnt_hi((unsigned)(msk >> 32),
                       __builtin_amdgcn_mbcnt_lo((unsigned)msk, 0u));
        int leader = __ffsll((long long)msk) - 1;
        unsigned base = 0;
        if ((int)pre == 0) base = atomicAdd(&cand_cnt[b], (unsigned)__popcll(msk));
        base = __shfl(base, leader, 64);
        cand[(size_t)b * AN + base + pre] = a;
        unsigned vbits = ve >> 1;
        float c[CN];
        float inv = row_prep(conf + idx * CN, c);
#pragma unroll
        for (int j = 0; j < CN; ++j) {
            float fo = cell_focal(c[j], inv, false);
            unsigned bits = focal_bits(fo);
            if (bits >= vbits) atomicAdd(&h[bits >> 20], 1u);
        }
    }
    __syncthreads();
    for (int i = tid; i < NBA; i += 256) {
        unsigned v = h[i];
        if (v) atomicAdd(&cnt1[b * NBA + i], v);
    }
}

// ---------- select1: level-1 boundary bin ----------
__global__ __launch_bounds__(256) void select1_kernel(
    const unsigned* __restrict__ cnt1, Chain* __restrict__ chains)
{
    int b = blockIdx.x, tid = threadIdx.x;
    Chain* ch = &chains[b];
    if (!ch->active) return;
    unsigned k = ch->k;
    const unsigned* cnt = cnt1 + (size_t)b * NBA;
    unsigned lc[8], ccnt = 0;
#pragma unroll
    for (int i = 0; i < 8; ++i) { lc[i] = cnt[tid * 8 + i]; ccnt += lc[i]; }
    __shared__ unsigned scnt[256];
    scnt[tid] = ccnt;
    __syncthreads();
    for (int off = 1; off < 256; off <<= 1) {
        unsigned vc = (tid + off < 256) ? scnt[tid + off] : 0u;
        __syncthreads();
        scnt[tid] += vc;
        __syncthreads();
    }
    unsigned total = scnt[0];
    unsigned aboveCnt = (tid < 255) ? scnt[tid + 1] : 0u;
    unsigned r = min(k, total);
    if (r == 0) return;
    if (aboveCnt < r && aboveCnt + ccnt >= r) {
        unsigned acc2 = aboveCnt;
        for (int i = 7; i >= 0; --i) {
            unsigned bc = lc[i];
            if (acc2 + bc >= r) { ch->b1 = (unsigned)(tid * 8 + i); ch->rem = r - acc2; break; }
            acc2 += bc;
        }
    }
}

// ---------- refine2 over candidates ----------
__global__ __launch_bounds__(256) void refine2_kernel(
    const float* __restrict__ conf, const int* __restrict__ cand,
    const unsigned* __restrict__ cand_cnt, Chain* __restrict__ chains,
    unsigned* __restrict__ cnt2, double* __restrict__ sum2)
{
    int b = blockIdx.y;
    if (!chains[b].active) return;
    unsigned b1 = chains[b].b1;
    unsigned m = cand_cnt[b];
    double sA = 0.0;
    for (unsigned i = blockIdx.x * 256u + threadIdx.x; i < m; i += 64u * 256u) {
        int a = cand[(size_t)b * AN + i];
        size_t idx = (size_t)b * AN + a;
        float c[CN];
        float inv = row_prep(conf + idx * CN, c);
#pragma unroll
        for (int j = 0; j < CN; ++j) {
            float fo = cell_focal(c[j], inv, false);
            unsigned bits = focal_bits(fo);
            unsigned hi = bits >> 20;
            if (hi > b1) sA += (double)fo;
            else if (hi == b1) {
                unsigned bin = (bits >> 8) & 0xFFFu;
                atomicAdd(&cnt2[b * NB2 + bin], 1u);
                atomicAdd(&sum2[b * NB2 + bin], (double)fo);
            }
        }
    }
#pragma unroll
    for (int off = 32; off; off >>= 1) sA += __shfl_down(sA, off, 64);
    __shared__ double sred[4];
    int wv = threadIdx.x >> 6, ln = threadIdx.x & 63;
    if (ln == 0) sred[wv] = sA;
    __syncthreads();
    if (threadIdx.x == 0) {
        double tt = sred[0] + sred[1] + sred[2] + sred[3];
        if (tt != 0.0) atomicAdd(&chains[b].sumAbove, tt);
    }
}

// ---------- select2 ----------
__global__ __launch_bounds__(256) void select2_kernel(
    const unsigned* __restrict__ cnt2, const double* __restrict__ sum2,
    Chain* __restrict__ chains)
{
    int b = blockIdx.x, tid = threadIdx.x;
    Chain* ch = &chains[b];
    if (!ch->active) return;
    unsigned rem = ch->rem;
    const unsigned* cnt = cnt2 + (size_t)b * NB2;
    const double* sum = sum2 + (size_t)b * NB2;
    unsigned lc[16], ccnt = 0; double ls[16], csum = 0.0;
#pragma unroll
    for (int i = 0; i < 16; ++i) {
        lc[i] = cnt[tid * 16 + i]; ls[i] = sum[tid * 16 + i];
        ccnt += lc[i]; csum += ls[i];
    }
    __shared__ unsigned scnt[256];
    __shared__ double ssum[256];
    scnt[tid] = ccnt; ssum[tid] = csum;
    __syncthreads();
    for (int off = 1; off < 256; off <<= 1) {
        unsigned vc = 0; double vs = 0.0;
        if (tid + off < 256) { vc = scnt[tid + off]; vs = ssum[tid + off]; }
        __syncthreads();
        scnt[tid] += vc; ssum[tid] += vs;
        __syncthreads();
    }
    unsigned total = scnt[0];
    unsigned aboveCnt = (tid < 255) ? scnt[tid + 1] : 0u;
    double aboveSum = (tid < 255) ? ssum[tid + 1] : 0.0;
    unsigned r = min(rem, total);
    if (r == 0) return;
    if (aboveCnt < r && aboveCnt + ccnt >= r) {
        unsigned acc2 = aboveCnt; double asum = aboveSum;
        for (int i = 15; i >= 0; --i) {
            unsigned bc = lc[i];
            if (acc2 + bc >= r) {
                ch->b2 = (unsigned)(tid * 16 + i);
                ch->rem = r - acc2;
                ch->sumAbove += asum;
                break;
            }
            acc2 += bc; asum += ls[i];
        }
    }
}

// ---------- refine3 over candidates ----------
__global__ __launch_bounds__(256) void refine3_kernel(
    const float* __restrict__ conf, const int* __restrict__ cand,
    const unsigned* __restrict__ cand_cnt, const Chain* __restrict__ chains,
    unsigned* __restrict__ cnt3, double* __restrict__ sum3)
{
    int b = blockIdx.y;
    if (!chains[b].active) return;
    unsigned hi24 = (chains[b].b1 << 12) | chains[b].b2;
    unsigned m = cand_cnt[b];
    for (unsigned i = blockIdx.x * 256u + threadIdx.x; i < m; i += 64u * 256u) {
        int a = cand[(size_t)b * AN + i];
        size_t idx = (size_t)b * AN + a;
        float c[CN];
        float inv = row_prep(conf + idx * CN, c);
#pragma unroll
        for (int j = 0; j < CN; ++j) {
            float fo = cell_focal(c[j], inv, false);
            unsigned bits = focal_bits(fo);
            if ((bits >> 8) == hi24) {
                unsigned bin = bits & 0xFFu;
                atomicAdd(&cnt3[b * NB3 + bin], 1u);
                atomicAdd(&sum3[b * NB3 + bin], (double)fo);
            }
        }
    }
}

// ---------- select3 (final) ----------
__global__ __launch_bounds__(256) void select3_kernel(
    const unsigned* __restrict__ cnt3, const double* __restrict__ sum3,
    Chain* __restrict__ chains)
{
    int b = blockIdx.x, tid = threadIdx.x;
    Chain* ch = &chains[b];
    if (!ch->active) return;
    unsigned rem = ch->rem;
    unsigned c = cnt3[b * NB3 + tid];
    double s = sum3[b * NB3 + tid];
    __shared__ unsigned scnt[256];
    __shared__ double ssum[256];
    scnt[tid] = c; ssum[tid] = s;
    __syncthreads();
    for (int off = 1; off < 256; off <<= 1) {
        unsigned vc = 0; double vs = 0.0;
        if (tid + off < 256) { vc = scnt[tid + off]; vs = ssum[tid + off]; }
        __syncthreads();
        scnt[tid] += vc; ssum[tid] += vs;
        __syncthreads();
    }
    unsigned total = scnt[0];
    unsigned aboveCnt = (tid < 255) ? scnt[tid + 1] : 0u;
    double aboveSum = (tid < 255) ? ssum[tid + 1] : 0.0;
    unsigned r = min(rem, total);
    if (r == 0) { if (tid == 0) ch->topk = ch->sumAbove; return; }
    if (aboveCnt < r && aboveCnt + c >= r) {
        unsigned vbits = (ch->b1 << 20) | (ch->b2 << 8) | (unsigned)tid;
        double v = (double)__uint_as_float(vbits);
        ch->topk = ch->sumAbove + aboveSum + (double)(r - aboveCnt) * v;
    }
}

// ---------- finalize (num_pos >= 1 always) ----------
__global__ void finalize_kernel(const Acc* __restrict__ acc,
                                const Chain* __restrict__ chains,
                                float* __restrict__ out)
{
    __shared__ double cl[BN], bl[BN];
    int t = threadIdx.x;
    if (t < BN) {
        unsigned np = acc[t].np, nn = acc[t].nn;
        double pos_sum = acc[t].pos_sum, bbox_sum = acc[t].bbox_sum;
        unsigned npc = max(np, 1u);
        double conf;
        if (nn > 0) {
            unsigned k = min(3u * np, nn);
            conf = (pos_sum + chains[t].topk) / (double)max(np + k, 1u);
        } else {
            conf = pos_sum / (double)npc;
        }
        cl[t] = conf;
        bl[t] = bbox_sum / (double)npc;
    }
    __syncthreads();
    if (t == 0) {
        double cs = 0, bs = 0;
        for (int i = 0; i < BN; ++i) { cs += cl[i]; bs += bl[i]; }
        cs /= BN; bs /= BN;
        out[0] = (float)(cs + bs);
        out[1] = (float)cs;
        out[2] = (float)bs;
    }
}

extern "C" void kernel_launch(void* const* d_in, const int* in_sizes, int n_in,
                              void* d_out, int out_size, void* d_ws, size_t ws_size,
                              hipStream_t stream)
{
    (void)in_sizes; (void)n_in; (void)out_size; (void)ws_size;
    const float*  conf    = (const float*)d_in[0];
    const float4* bboxp   = (const float4*)d_in[1];
    const float4* anchors = (const float4*)d_in[2];
    const float4* tboxes  = (const float4*)d_in[3];
    const int*    tlabels = (const int*)d_in[4];
    float* out = (float*)d_out;
    char* ws = (char*)d_ws;
    size_t off = 0;
    auto alloc = [&](size_t bytes) -> void* {
        void* p = (void*)(ws + off);
        off = (off + bytes + 255) & ~(size_t)255;
        return p;
    };
    float*          max_iou  = (float*)alloc((size_t)BN * AN * 4);
    unsigned char*  bestt    = (unsigned char*)alloc((size_t)BN * AN);
    unsigned*       maxb     = (unsigned*)alloc((size_t)BN * AN * 4);
    int*            cand     = (int*)alloc((size_t)BN * AN * 4);
    BlockAcc*       blockAcc = (BlockAcc*)alloc((size_t)BN * 256 * sizeof(BlockAcc));
    Acc*            acc      = (Acc*)alloc(BN * sizeof(Acc));
    size_t zstart = off;
    unsigned long long* gbest = (unsigned long long*)alloc((size_t)BN * TN * 8);
    Delta*    delta    = (Delta*)alloc(BN * sizeof(Delta));
    Chain*    chains   = (Chain*)alloc(BN * sizeof(Chain));
    unsigned* ahist    = (unsigned*)alloc((size_t)BN * NBA * 4);
    unsigned* cand_cnt = (unsigned*)alloc((size_t)BN * 4);
    unsigned* cnt1     = (unsigned*)alloc((size_t)BN * NBA * 4);
    unsigned* cnt2     = (unsigned*)alloc((size_t)BN * NB2 * 4);
    double*   sum2     = (double*)alloc((size_t)BN * NB2 * 8);
    unsigned* cnt3     = (unsigned*)alloc((size_t)BN * NB3 * 4);
    double*   sum3     = (double*)alloc((size_t)BN * NB3 * 8);
    size_t zbytes = off - zstart;
    hipMemsetAsync(ws + zstart, 0, zbytes, stream);

    dim3 gridA(AN / 256, BN);
    dim3 gridR(64, BN);
    main_kernel<<<gridA, 256, 0, stream>>>(conf, bboxp, anchors, tboxes, tlabels,
                                           max_iou, bestt, gbest, ahist, maxb, blockAcc);
    force_fix_kernel<<<BN, 64, 0, stream>>>(conf, bboxp, tboxes, tlabels, max_iou, bestt,
                                            gbest, ahist, maxb, delta);
    select0_kernel<<<BN, 256, 0, stream>>>(blockAcc, delta, ahist, acc, chains);
    collect_kernel<<<gridA, 256, 0, stream>>>(conf, maxb, chains, cand, cand_cnt, cnt1);
    select1_kernel<<<BN, 256, 0, stream>>>(cnt1, chains);
    refine2_kernel<<<gridR, 256, 0, stream>>>(conf, cand, cand_cnt, chains, cnt2, sum2);
    select2_kernel<<<BN, 256, 0, stream>>>(cnt2, sum2, chains);
    refine3_kernel<<<gridR, 256, 0, stream>>>(conf, cand, cand_cnt, chains, cnt3, sum3);
    select3_kernel<<<BN, 256, 0, stream>>>(cnt3, sum3, chains);
    finalize_kernel<<<1, 64, 0, stream>>>(acc, chains, out);
}

// Round 5
// 285.005 us; speedup vs baseline: 1.8681x; 1.4912x over previous
//
#include <hip/hip_runtime.h>

// DetectionLoss: B=16, A=65536, T=32, C=21.
// R5: collect split into cheap coalesced compaction (block-aggregated ballot)
// + dense candidate histogram; tree-reduced softmax (shared across kernels for
// bit-identical recompute). Pipeline: fused main (match+focal+anchor-hist) ->
// force_fix -> select0 (threshold) -> compact -> hist1 -> select1 -> refine2 ->
// select2 -> refine3 -> select3 -> finalize.

#define AN 65536
#define BN 16
#define TN 32
#define CN 21
#define NBA 2048   // bits>>20 of positive float
#define NB2 4096
#define NB3 256

struct Acc   { double pos_sum; double bbox_sum; unsigned np; unsigned nn; };
struct Delta { double dpos; double dbbox; int dnp; int dnn; };
struct Chain { double sumAbove; double topk; unsigned active; unsigned k; unsigned ve;
               unsigned b1; unsigned b2; unsigned rem; };
struct BlockAcc { float pos_sum; float bbox_sum; unsigned np; unsigned nn; };

// ---------- shared math: bit-identical across kernels (_rn intrinsics, shared fn) ----------
__device__ __forceinline__ float row_prep(const float* __restrict__ row, float* __restrict__ c) {
#pragma unroll
    for (int j = 0; j < CN; ++j) c[j] = row[j];
    float m1[10];
#pragma unroll
    for (int j = 0; j < 10; ++j) m1[j] = fmaxf(c[j], c[j + 10]);
    float m2[5];
#pragma unroll
    for (int j = 0; j < 5; ++j) m2[j] = fmaxf(m1[j], m1[j + 5]);
    float ma = fmaxf(m2[0], m2[1]), mb = fmaxf(m2[2], m2[3]);
    float m = fmaxf(fmaxf(ma, mb), fmaxf(m2[4], c[20]));
#pragma unroll
    for (int j = 0; j < CN; ++j) c[j] = __expf(__fsub_rn(c[j], m));
    float s1[10];
#pragma unroll
    for (int j = 0; j < 10; ++j) s1[j] = __fadd_rn(c[j], c[j + 10]);
    float s2[5];
#pragma unroll
    for (int j = 0; j < 5; ++j) s2[j] = __fadd_rn(s1[j], s1[j + 5]);
    float sa = __fadd_rn(s2[0], s2[1]), sb = __fadd_rn(s2[2], s2[3]);
    float s = __fadd_rn(__fadd_rn(sa, sb), __fadd_rn(s2[4], c[20]));
    return 1.0f / s;
}
__device__ __forceinline__ float cell_focal(float cexp, float inv, bool cellpos) {
    float p = __fmul_rn(cexp, inv);
    float pt = cellpos ? p : __fsub_rn(1.0f, p);
    float af = cellpos ? 0.25f : 0.75f;
    float om = __fsub_rn(1.0f, pt);
    float lg = __logf(fmaxf(pt, 1e-6f));
    return __fmul_rn(__fmul_rn(__fmul_rn(-af, om), om), lg);
}
__device__ __forceinline__ unsigned focal_bits(float fo) {
    unsigned bits = __float_as_uint(fo);
    if (bits == 0x80000000u) bits = 0u;   // canonicalize -0.0
    return bits;
}
__device__ __forceinline__ float iou_pair(float4 A, float aa, float4 T, float ta) {
    float x1 = fmaxf(A.x, T.x), y1 = fmaxf(A.y, T.y);
    float x2 = fminf(A.z, T.z), y2 = fminf(A.w, T.w);
    float inter = fmaxf(x2 - x1, 0.f) * fmaxf(y2 - y1, 0.f);
    return inter / (aa + ta - inter + 1e-6f);
}
__device__ __forceinline__ float bbox_per(float4 b1, float4 b2) {
    float x1 = fmaxf(b1.x, b2.x), y1 = fmaxf(b1.y, b2.y);
    float x2 = fminf(b1.z, b2.z), y2 = fminf(b1.w, b2.w);
    float inter = fmaxf(x2 - x1, 0.f) * fmaxf(y2 - y1, 0.f);
    float a1 = (b1.z - b1.x) * (b1.w - b1.y);
    float a2 = (b2.z - b2.x) * (b2.w - b2.y);
    float un = a1 + a2 - inter;
    float iou = inter / (un + 1e-6f);
    float ex1 = fminf(b1.x, b2.x), ey1 = fminf(b1.y, b2.y);
    float ex2 = fmaxf(b1.z, b2.z), ey2 = fmaxf(b1.w, b2.w);
    float enc = (ex2 - ex1) * (ey2 - ey1);
    float giou = iou - (enc - un) / (enc + 1e-6f);
    float gl = 1.0f - giou;
    float l1 = 0.f, d, ad;
    d = b1.x - b2.x; ad = fabsf(d); l1 += (ad < 1.f) ? (0.5f * d * d) : (ad - 0.5f);
    d = b1.y - b2.y; ad = fabsf(d); l1 += (ad < 1.f) ? (0.5f * d * d) : (ad - 0.5f);
    d = b1.z - b2.z; ad = fabsf(d); l1 += (ad < 1.f) ? (0.5f * d * d) : (ad - 0.5f);
    d = b1.w - b2.w; ad = fabsf(d); l1 += (ad < 1.f) ? (0.5f * d * d) : (ad - 0.5f);
    return gl + 0.5f * (l1 * 0.25f);
}

// ---------- fused main: match + force-argmax + focal + anchor hist ----------
__global__ __launch_bounds__(256) void main_kernel(
    const float* __restrict__ conf, const float4* __restrict__ bboxp,
    const float4* __restrict__ anchors, const float4* __restrict__ tboxes,
    const int* __restrict__ tlabels,
    float* __restrict__ max_iou, unsigned char* __restrict__ best_t,
    unsigned long long* __restrict__ gbest,
    unsigned* __restrict__ ahist, unsigned* __restrict__ maxb,
    BlockAcc* __restrict__ blockAcc)
{
    __shared__ float4 tbS[TN];
    __shared__ float4 aS[256];
    __shared__ int tlS[TN];
    __shared__ unsigned ah[NBA];           // 8 KB
    __shared__ float pbV[TN][8];
    __shared__ int   pbA[TN][8];
    __shared__ float rF[2][4];
    __shared__ unsigned rI[2][4];
    int b = blockIdx.y, tid = threadIdx.x;
    int a = blockIdx.x * 256 + tid;
    for (int i = tid; i < NBA; i += 256) ah[i] = 0u;
    if (tid < TN) { tbS[tid] = tboxes[b * TN + tid]; tlS[tid] = tlabels[b * TN + tid]; }
    float4 ab = anchors[a];
    aS[tid] = ab;
    __syncthreads();

    // phase 1: per-anchor max IoU over targets
    float a1 = (ab.z - ab.x) * (ab.w - ab.y);
    float best = -1.0f; int bt = 0;
#pragma unroll
    for (int t = 0; t < TN; ++t) {
        float4 T = tbS[t];
        float ta = (T.z - T.x) * (T.w - T.y);
        float iou = iou_pair(ab, a1, T, ta);
        if (iou > best) { best = iou; bt = t; }   // strict >: first-occurrence argmax
    }
    size_t idx = (size_t)b * AN + a;
    max_iou[idx] = best;
    best_t[idx] = (unsigned char)bt;

    // phase 2: per-target best anchor within block (recompute from LDS)
    {
        int t = tid & 31, pp = tid >> 5;
        float4 T = tbS[t];
        float ta = (T.z - T.x) * (T.w - T.y);
        float bv = -1.f; int ba = 0;
        for (int r = pp * 32; r < pp * 32 + 32; ++r) {
            float4 A = aS[r];
            float aa = (A.z - A.x) * (A.w - A.y);
            float iou = iou_pair(A, aa, T, ta);
            if (iou > bv) { bv = iou; ba = r; }
        }
        pbV[t][pp] = bv; pbA[t][pp] = ba;
    }
    __syncthreads();
    if (tid < TN) {
        float bv = -1.f; int ba = 0;
#pragma unroll
        for (int pp = 0; pp < 8; ++pp) {
            float v = pbV[tid][pp];
            if (v > bv) { bv = v; ba = pbA[tid][pp]; }
        }
        unsigned ga = blockIdx.x * 256 + (unsigned)ba;
        unsigned long long key =
            (((unsigned long long)__float_as_uint(bv)) << 32) | (unsigned long long)(unsigned)(~ga);
        atomicMax(&gbest[b * TN + tid], key);   // tie -> smaller anchor idx
    }

    // phase 3: focal (threshold classification; forced anchors fixed later)
    bool posA = best >= 0.5f;
    bool negA = best < 0.4f;
    float fs = 0.f, bper = 0.f;
    unsigned mbenc = 0u;
    if (posA || negA) {
        int label = posA ? tlS[bt] : -1;
        float c[CN];
        float inv = row_prep(conf + idx * CN, c);
        unsigned mb = 0u;
#pragma unroll
        for (int j = 0; j < CN; ++j) {
            float fo = cell_focal(c[j], inv, j == label);
            fs += fo;
            mb = max(mb, focal_bits(fo));
        }
        if (negA) { mbenc = (mb << 1) | 1u; atomicAdd(&ah[mb >> 20], 1u); fs = 0.f; }
        else      { bper = bbox_per(bboxp[idx], tbS[bt]); }
    }
    maxb[idx] = mbenc;

    // block reduce {pos_sum, bbox_sum, np, nn} -> plain store
    float vpos = fs, vb = bper;
    unsigned inp = posA ? 1u : 0u, inn = negA ? 1u : 0u;
#pragma unroll
    for (int off = 32; off; off >>= 1) {
        vpos += __shfl_down(vpos, off, 64);
        vb   += __shfl_down(vb,   off, 64);
        inp  += __shfl_down(inp,  off, 64);
        inn  += __shfl_down(inn,  off, 64);
    }
    int wv = tid >> 6, ln = tid & 63;
    if (ln == 0) { rF[0][wv] = vpos; rF[1][wv] = vb; rI[0][wv] = inp; rI[1][wv] = inn; }
    __syncthreads();
    if (tid == 0) {
        BlockAcc ba2;
        ba2.pos_sum = rF[0][0] + rF[0][1] + rF[0][2] + rF[0][3];
        ba2.bbox_sum = rF[1][0] + rF[1][1] + rF[1][2] + rF[1][3];
        ba2.np = rI[0][0] + rI[0][1] + rI[0][2] + rI[0][3];
        ba2.nn = rI[1][0] + rI[1][1] + rI[1][2] + rI[1][3];
        blockAcc[b * 256 + blockIdx.x] = ba2;
    }
    for (int i = tid; i < NBA; i += 256) {
        unsigned v = ah[i];
        if (v) atomicAdd(&ahist[b * NBA + i], v);
    }
}

// ---------- force-match fix: <=32 anchors/image ----------
__global__ void force_fix_kernel(
    const float* __restrict__ conf, const float4* __restrict__ bboxp,
    const float4* __restrict__ tboxes, const int* __restrict__ tlabels,
    const float* __restrict__ max_iou, const unsigned char* __restrict__ best_t,
    const unsigned long long* __restrict__ gbest,
    unsigned* __restrict__ ahist, unsigned* __restrict__ maxb,
    Delta* __restrict__ delta)
{
    __shared__ unsigned gaS[TN];
    __shared__ float4 tbS[TN];
    __shared__ int tlS[TN];
    int b = blockIdx.x, t = threadIdx.x;
    if (t < TN) {
        gaS[t] = ~(unsigned)(gbest[b * TN + t] & 0xFFFFFFFFull);
        tbS[t] = tboxes[b * TN + t];
        tlS[t] = tlabels[b * TN + t];
    }
    __syncthreads();
    if (t >= TN) return;
    unsigned ga = gaS[t];
    for (int u = 0; u < t; ++u) if (gaS[u] == ga) return;   // dedupe
    size_t idx = (size_t)b * AN + ga;
    float mi = max_iou[idx];
    if (mi >= 0.5f) return;
    int bt = best_t[idx];
    int label = tlS[bt];
    float c[CN];
    float inv = row_prep(conf + idx * CN, c);
    float fs = 0.f;
#pragma unroll
    for (int j = 0; j < CN; ++j) fs += cell_focal(c[j], inv, j == label);
    float bper = bbox_per(bboxp[idx], tbS[bt]);
    atomicAdd(&delta[b].dpos, (double)fs);
    atomicAdd(&delta[b].dbbox, (double)bper);
    atomicAdd(&delta[b].dnp, 1);
    if (mi < 0.4f) {
        unsigned mb = maxb[idx];
        atomicSub(&ahist[b * NBA + (mb >> 21)], 1u);
        maxb[idx] = 0u;
        atomicAdd(&delta[b].dnn, -1);
    }
}

// ---------- select0: totals + anchor-max threshold ----------
__global__ __launch_bounds__(256) void select0_kernel(
    const BlockAcc* __restrict__ blockAcc, const Delta* __restrict__ delta,
    const unsigned* __restrict__ ahist, Acc* __restrict__ acc,
    Chain* __restrict__ chains)
{
    int b = blockIdx.x, tid = threadIdx.x;
    BlockAcc ba = blockAcc[b * 256 + tid];
    double ps = (double)ba.pos_sum, bs = (double)ba.bbox_sum;
    unsigned np = ba.np, nn = ba.nn;
#pragma unroll
    for (int off = 32; off; off >>= 1) {
        ps += __shfl_down(ps, off, 64);
        bs += __shfl_down(bs, off, 64);
        np += __shfl_down(np, off, 64);
        nn += __shfl_down(nn, off, 64);
    }
    __shared__ double sps[4], sbs[4];
    __shared__ unsigned snp[4], snn[4];
    __shared__ unsigned s_np, s_nn;
    int wv = tid >> 6, ln = tid & 63;
    if (ln == 0) { sps[wv] = ps; sbs[wv] = bs; snp[wv] = np; snn[wv] = nn; }
    __syncthreads();
    if (tid == 0) {
        Acc A;
        A.pos_sum = sps[0] + sps[1] + sps[2] + sps[3] + delta[b].dpos;
        A.bbox_sum = sbs[0] + sbs[1] + sbs[2] + sbs[3] + delta[b].dbbox;
        A.np = (unsigned)((int)(snp[0] + snp[1] + snp[2] + snp[3]) + delta[b].dnp);
        A.nn = (unsigned)((int)(snn[0] + snn[1] + snn[2] + snn[3]) + delta[b].dnn);
        acc[b] = A;
        s_np = A.np; s_nn = A.nn;
    }
    __syncthreads();
    unsigned npT = s_np, nnT = s_nn;
    if (nnT == 0) return;
    unsigned k = min(3u * npT, nnT);
    const unsigned* h = ahist + b * NBA;
    unsigned lc[8], ccnt = 0;
#pragma unroll
    for (int i = 0; i < 8; ++i) { lc[i] = h[tid * 8 + i]; ccnt += lc[i]; }
    __shared__ unsigned scnt[256];
    scnt[tid] = ccnt;
    __syncthreads();
    for (int off = 1; off < 256; off <<= 1) {
        unsigned vc = (tid + off < 256) ? scnt[tid + off] : 0u;
        __syncthreads();
        scnt[tid] += vc;
        __syncthreads();
    }
    unsigned aboveCnt = (tid < 255) ? scnt[tid + 1] : 0u;
    if (aboveCnt < k && aboveCnt + ccnt >= k) {
        unsigned acc2 = aboveCnt;
        for (int i = 7; i >= 0; --i) {
            if (acc2 + lc[i] >= k) {
                unsigned bin = (unsigned)(tid * 8 + i);
                chains[b].active = 1;
                chains[b].k = k;
                chains[b].ve = (bin << 21) | 1u;   // encoded threshold
                break;
            }
            acc2 += lc[i];
        }
    }
}

// ---------- compact: candidate anchors only (no softmax, no hist) ----------
__global__ __launch_bounds__(256) void compact_kernel(
    const unsigned* __restrict__ maxb, const Chain* __restrict__ chains,
    int* __restrict__ cand, unsigned* __restrict__ cand_cnt)
{
    int b = blockIdx.y, tid = threadIdx.x;
    if (!chains[b].active) return;
    unsigned ve = chains[b].ve;
    int a = blockIdx.x * 256 + tid;
    size_t idx = (size_t)b * AN + a;
    bool q = (maxb[idx] >= ve);          // maxb==0 for non-neg anchors
    unsigned long long msk = __ballot(q);   // all lanes active here
    int wv = tid >> 6, ln = tid & 63;
    __shared__ unsigned wbase[4];
    __shared__ unsigned nonzero;
    if (tid == 0) nonzero = 0;
    __syncthreads();
    if (ln == 0) { wbase[wv] = (unsigned)__popcll(msk); if (msk) atomicOr(&nonzero, 1u); }
    __syncthreads();
    if (!nonzero) return;
    if (tid == 0) {
        unsigned tot = wbase[0] + wbase[1] + wbase[2] + wbase[3];
        unsigned base = atomicAdd(&cand_cnt[b], tot);
        unsigned run = base;
        for (int w = 0; w < 4; ++w) { unsigned t2 = wbase[w]; wbase[w] = run; run += t2; }
    }
    __syncthreads();
    if (q) {
        unsigned pre = (unsigned)__popcll(msk & ((ln == 63) ? ~0ULL >> 1 : ((1ULL << (ln + 1)) - 1ULL) >> 1));
        // pre = count of set bits below ln
        cand[(size_t)b * AN + wbase[wv] + pre] = a;
    }
}

// ---------- hist1: L1 cell histogram over DENSE candidate list ----------
__global__ __launch_bounds__(256) void hist1_kernel(
    const float* __restrict__ conf, const int* __restrict__ cand,
    const unsigned* __restrict__ cand_cnt, const Chain* __restrict__ chains,
    unsigned* __restrict__ cnt1)
{
    int b = blockIdx.y, tid = threadIdx.x;
    if (!chains[b].active) return;
    unsigned vbits = chains[b].ve >> 1;     // boundary-bin lower edge (bits)
    unsigned m = cand_cnt[b];
    __shared__ unsigned h[NBA];
    for (int i = tid; i < NBA; i += 256) h[i] = 0u;
    __syncthreads();
    for (unsigned i = blockIdx.x * 256u + tid; i < m; i += 32u * 256u) {
        int a = cand[(size_t)b * AN + i];
        size_t idx = (size_t)b * AN + a;
        float c[CN];
        float inv = row_prep(conf + idx * CN, c);
#pragma unroll
        for (int j = 0; j < CN; ++j) {
            float fo = cell_focal(c[j], inv, false);
            unsigned bits = focal_bits(fo);
            if (bits >= vbits) atomicAdd(&h[bits >> 20], 1u);
        }
    }
    __syncthreads();
    for (int i = tid; i < NBA; i += 256) {
        unsigned v = h[i];
        if (v) atomicAdd(&cnt1[b * NBA + i], v);
    }
}

// ---------- select1: level-1 boundary bin ----------
__global__ __launch_bounds__(256) void select1_kernel(
    const unsigned* __restrict__ cnt1, Chain* __restrict__ chains)
{
    int b = blockIdx.x, tid = threadIdx.x;
    Chain* ch = &chains[b];
    if (!ch->active) return;
    unsigned k = ch->k;
    const unsigned* cnt = cnt1 + (size_t)b * NBA;
    unsigned lc[8], ccnt = 0;
#pragma unroll
    for (int i = 0; i < 8; ++i) { lc[i] = cnt[tid * 8 + i]; ccnt += lc[i]; }
    __shared__ unsigned scnt[256];
    scnt[tid] = ccnt;
    __syncthreads();
    for (int off = 1; off < 256; off <<= 1) {
        unsigned vc = (tid + off < 256) ? scnt[tid + off] : 0u;
        __syncthreads();
        scnt[tid] += vc;
        __syncthreads();
    }
    unsigned total = scnt[0];
    unsigned aboveCnt = (tid < 255) ? scnt[tid + 1] : 0u;
    unsigned r = min(k, total);
    if (r == 0) return;
    if (aboveCnt < r && aboveCnt + ccnt >= r) {
        unsigned acc2 = aboveCnt;
        for (int i = 7; i >= 0; --i) {
            unsigned bc = lc[i];
            if (acc2 + bc >= r) { ch->b1 = (unsigned)(tid * 8 + i); ch->rem = r - acc2; break; }
            acc2 += bc;
        }
    }
}

// ---------- refine2 over candidates ----------
__global__ __launch_bounds__(256) void refine2_kernel(
    const float* __restrict__ conf, const int* __restrict__ cand,
    const unsigned* __restrict__ cand_cnt, Chain* __restrict__ chains,
    unsigned* __restrict__ cnt2, double* __restrict__ sum2)
{
    int b = blockIdx.y;
    if (!chains[b].active) return;
    unsigned b1 = chains[b].b1;
    unsigned m = cand_cnt[b];
    double sA = 0.0;
    for (unsigned i = blockIdx.x * 256u + threadIdx.x; i < m; i += 32u * 256u) {
        int a = cand[(size_t)b * AN + i];
        size_t idx = (size_t)b * AN + a;
        float c[CN];
        float inv = row_prep(conf + idx * CN, c);
#pragma unroll
        for (int j = 0; j < CN; ++j) {
            float fo = cell_focal(c[j], inv, false);
            unsigned bits = focal_bits(fo);
            unsigned hi = bits >> 20;
            if (hi > b1) sA += (double)fo;
            else if (hi == b1) {
                unsigned bin = (bits >> 8) & 0xFFFu;
                atomicAdd(&cnt2[b * NB2 + bin], 1u);
                atomicAdd(&sum2[b * NB2 + bin], (double)fo);
            }
        }
    }
#pragma unroll
    for (int off = 32; off; off >>= 1) sA += __shfl_down(sA, off, 64);
    __shared__ double sred[4];
    int wv = threadIdx.x >> 6, ln = threadIdx.x & 63;
    if (ln == 0) sred[wv] = sA;
    __syncthreads();
    if (threadIdx.x == 0) {
        double tt = sred[0] + sred[1] + sred[2] + sred[3];
        if (tt != 0.0) atomicAdd(&chains[b].sumAbove, tt);
    }
}

// ---------- select2 ----------
__global__ __launch_bounds__(256) void select2_kernel(
    const unsigned* __restrict__ cnt2, const double* __restrict__ sum2,
    Chain* __restrict__ chains)
{
    int b = blockIdx.x, tid = threadIdx.x;
    Chain* ch = &chains[b];
    if (!ch->active) return;
    unsigned rem = ch->rem;
    const unsigned* cnt = cnt2 + (size_t)b * NB2;
    const double* sum = sum2 + (size_t)b * NB2;
    unsigned lc[16], ccnt = 0; double ls[16], csum = 0.0;
#pragma unroll
    for (int i = 0; i < 16; ++i) {
        lc[i] = cnt[tid * 16 + i]; ls[i] = sum[tid * 16 + i];
        ccnt += lc[i]; csum += ls[i];
    }
    __shared__ unsigned scnt[256];
    __shared__ double ssum[256];
    scnt[tid] = ccnt; ssum[tid] = csum;
    __syncthreads();
    for (int off = 1; off < 256; off <<= 1) {
        unsigned vc = 0; double vs = 0.0;
        if (tid + off < 256) { vc = scnt[tid + off]; vs = ssum[tid + off]; }
        __syncthreads();
        scnt[tid] += vc; ssum[tid] += vs;
        __syncthreads();
    }
    unsigned total = scnt[0];
    unsigned aboveCnt = (tid < 255) ? scnt[tid + 1] : 0u;
    double aboveSum = (tid < 255) ? ssum[tid + 1] : 0.0;
    unsigned r = min(rem, total);
    if (r == 0) return;
    if (aboveCnt < r && aboveCnt + ccnt >= r) {
        unsigned acc2 = aboveCnt; double asum = aboveSum;
        for (int i = 15; i >= 0; --i) {
            unsigned bc = lc[i];
            if (acc2 + bc >= r) {
                ch->b2 = (unsigned)(tid * 16 + i);
                ch->rem = r - acc2;
                ch->sumAbove += asum;
                break;
            }
            acc2 += bc; asum += ls[i];
        }
    }
}

// ---------- refine3 over candidates ----------
__global__ __launch_bounds__(256) void refine3_kernel(
    const float* __restrict__ conf, const int* __restrict__ cand,
    const unsigned* __restrict__ cand_cnt, const Chain* __restrict__ chains,
    unsigned* __restrict__ cnt3, double* __restrict__ sum3)
{
    int b = blockIdx.y;
    if (!chains[b].active) return;
    unsigned hi24 = (chains[b].b1 << 12) | chains[b].b2;
    unsigned m = cand_cnt[b];
    for (unsigned i = blockIdx.x * 256u + threadIdx.x; i < m; i += 32u * 256u) {
        int a = cand[(size_t)b * AN + i];
        size_t idx = (size_t)b * AN + a;
        float c[CN];
        float inv = row_prep(conf + idx * CN, c);
#pragma unroll
        for (int j = 0; j < CN; ++j) {
            float fo = cell_focal(c[j], inv, false);
            unsigned bits = focal_bits(fo);
            if ((bits >> 8) == hi24) {
                unsigned bin = bits & 0xFFu;
                atomicAdd(&cnt3[b * NB3 + bin], 1u);
                atomicAdd(&sum3[b * NB3 + bin], (double)fo);
            }
        }
    }
}

// ---------- select3 (final) ----------
__global__ __launch_bounds__(256) void select3_kernel(
    const unsigned* __restrict__ cnt3, const double* __restrict__ sum3,
    Chain* __restrict__ chains)
{
    int b = blockIdx.x, tid = threadIdx.x;
    Chain* ch = &chains[b];
    if (!ch->active) return;
    unsigned rem = ch->rem;
    unsigned c = cnt3[b * NB3 + tid];
    double s = sum3[b * NB3 + tid];
    __shared__ unsigned scnt[256];
    __shared__ double ssum[256];
    scnt[tid] = c; ssum[tid] = s;
    __syncthreads();
    for (int off = 1; off < 256; off <<= 1) {
        unsigned vc = 0; double vs = 0.0;
        if (tid + off < 256) { vc = scnt[tid + off]; vs = ssum[tid + off]; }
        __syncthreads();
        scnt[tid] += vc; ssum[tid] += vs;
        __syncthreads();
    }
    unsigned total = scnt[0];
    unsigned aboveCnt = (tid < 255) ? scnt[tid + 1] : 0u;
    double aboveSum = (tid < 255) ? ssum[tid + 1] : 0.0;
    unsigned r = min(rem, total);
    if (r == 0) { if (tid == 0) ch->topk = ch->sumAbove; return; }
    if (aboveCnt < r && aboveCnt + c >= r) {
        unsigned vbits = (ch->b1 << 20) | (ch->b2 << 8) | (unsigned)tid;
        double v = (double)__uint_as_float(vbits);
        ch->topk = ch->sumAbove + aboveSum + (double)(r - aboveCnt) * v;
    }
}

// ---------- finalize ----------
__global__ void finalize_kernel(const Acc* __restrict__ acc,
                                const Chain* __restrict__ chains,
                                float* __restrict__ out)
{
    __shared__ double cl[BN], bl[BN];
    int t = threadIdx.x;
    if (t < BN) {
        unsigned np = acc[t].np, nn = acc[t].nn;
        double pos_sum = acc[t].pos_sum, bbox_sum = acc[t].bbox_sum;
        unsigned npc = max(np, 1u);
        double conf;
        if (nn > 0) {
            unsigned k = min(3u * np, nn);
            conf = (pos_sum + chains[t].topk) / (double)max(np + k, 1u);
        } else {
            conf = pos_sum / (double)npc;
        }
        cl[t] = conf;
        bl[t] = bbox_sum / (double)npc;
    }
    __syncthreads();
    if (t == 0) {
        double cs = 0, bs = 0;
        for (int i = 0; i < BN; ++i) { cs += cl[i]; bs += bl[i]; }
        cs /= BN; bs /= BN;
        out[0] = (float)(cs + bs);
        out[1] = (float)cs;
        out[2] = (float)bs;
    }
}

extern "C" void kernel_launch(void* const* d_in, const int* in_sizes, int n_in,
                              void* d_out, int out_size, void* d_ws, size_t ws_size,
                              hipStream_t stream)
{
    (void)in_sizes; (void)n_in; (void)out_size; (void)ws_size;
    const float*  conf    = (const float*)d_in[0];
    const float4* bboxp   = (const float4*)d_in[1];
    const float4* anchors = (const float4*)d_in[2];
    const float4* tboxes  = (const float4*)d_in[3];
    const int*    tlabels = (const int*)d_in[4];
    float* out = (float*)d_out;
    char* ws = (char*)d_ws;
    size_t off = 0;
    auto alloc = [&](size_t bytes) -> void* {
        void* p = (void*)(ws + off);
        off = (off + bytes + 255) & ~(size_t)255;
        return p;
    };
    float*          max_iou  = (float*)alloc((size_t)BN * AN * 4);
    unsigned char*  bestt    = (unsigned char*)alloc((size_t)BN * AN);
    unsigned*       maxb     = (unsigned*)alloc((size_t)BN * AN * 4);
    int*            cand     = (int*)alloc((size_t)BN * AN * 4);
    BlockAcc*       blockAcc = (BlockAcc*)alloc((size_t)BN * 256 * sizeof(BlockAcc));
    Acc*            acc      = (Acc*)alloc(BN * sizeof(Acc));
    size_t zstart = off;
    unsigned long long* gbest = (unsigned long long*)alloc((size_t)BN * TN * 8);
    Delta*    delta    = (Delta*)alloc(BN * sizeof(Delta));
    Chain*    chains   = (Chain*)alloc(BN * sizeof(Chain));
    unsigned* ahist    = (unsigned*)alloc((size_t)BN * NBA * 4);
    unsigned* cand_cnt = (unsigned*)alloc((size_t)BN * 4);
    unsigned* cnt1     = (unsigned*)alloc((size_t)BN * NBA * 4);
    unsigned* cnt2     = (unsigned*)alloc((size_t)BN * NB2 * 4);
    double*   sum2     = (double*)alloc((size_t)BN * NB2 * 8);
    unsigned* cnt3     = (unsigned*)alloc((size_t)BN * NB3 * 4);
    double*   sum3     = (double*)alloc((size_t)BN * NB3 * 8);
    size_t zbytes = off - zstart;
    hipMemsetAsync(ws + zstart, 0, zbytes, stream);

    dim3 gridA(AN / 256, BN);
    dim3 gridH(32, BN);
    main_kernel<<<gridA, 256, 0, stream>>>(conf, bboxp, anchors, tboxes, tlabels,
                                           max_iou, bestt, gbest, ahist, maxb, blockAcc);
    force_fix_kernel<<<BN, 64, 0, stream>>>(conf, bboxp, tboxes, tlabels, max_iou, bestt,
                                            gbest, ahist, maxb, delta);
    select0_kernel<<<BN, 256, 0, stream>>>(blockAcc, delta, ahist, acc, chains);
    compact_kernel<<<gridA, 256, 0, stream>>>(maxb, chains, cand, cand_cnt);
    hist1_kernel<<<gridH, 256, 0, stream>>>(conf, cand, cand_cnt, chains, cnt1);
    select1_kernel<<<BN, 256, 0, stream>>>(cnt1, chains);
    refine2_kernel<<<gridH, 256, 0, stream>>>(conf, cand, cand_cnt, chains, cnt2, sum2);
    select2_kernel<<<BN, 256, 0, stream>>>(cnt2, sum2, chains);
    refine3_kernel<<<gridH, 256, 0, stream>>>(conf, cand, cand_cnt, chains, cnt3, sum3);
    select3_kernel<<<BN, 256, 0, stream>>>(cnt3, sum3, chains);
    finalize_kernel<<<1, 64, 0, stream>>>(acc, chains, out);
}